// Round 9
// baseline (296.305 us; speedup 1.0000x reference)
//
#include <hip/hip_runtime.h>
#include <math.h>

// Problem constants
#define BB 4
#define SS 1024
#define DD 256
#define HH 8
#define HD 32
#define D3 768
#define MLP 1024
#define NTOK (BB * SS)   // 4096
#define NSEG 4           // split-K segments for full attention (load-bearing
                         // for TLP — round-7 post-mortem: nseg=1 regressed)

typedef __attribute__((ext_vector_type(8))) short short8;
typedef __attribute__((ext_vector_type(4))) float f32x4;

__device__ __forceinline__ unsigned short f2bfu(float f) {
    union { float f; unsigned i; } u; u.f = f;
    unsigned r = u.i + 0x7fffu + ((u.i >> 16) & 1u);   // RNE
    return (unsigned short)(r >> 16);
}
__device__ __forceinline__ float bfu2f(unsigned short h) {
    union { unsigned i; float f; } u; u.i = ((unsigned)h) << 16; return u.f;
}

// ---------------------------------------------------------------------------
// Fused prep: weights fp32->bf16 (+lo for Win_a layer 0)  AND  x+pos encode.
// Round 9: 4 elems/thread (float4 loads / ushort4 stores) — prep is serial
// before the whole chain and was scalar 4B/lane (G13: ~2x loss on a
// memory-bound kernel). All array boundaries & WL0 are /4 so each float4
// stays in one source. Bit-exact per element.
#define W_TOT 2097152
#define WL0   196608   // 768*256 = Win_a layer 0
#define WBLK4 (W_TOT / 1024)          // 2048 weight blocks (4 elems/thread)
#define PBLK4 (NTOK * DD / 1024)      // 1024 pos blocks
__global__ __launch_bounds__(256) void prep_kernel(
    const float* __restrict__ a0, const float* __restrict__ a1,
    const float* __restrict__ a2, const float* __restrict__ a3,
    const float* __restrict__ a4, const float* __restrict__ a5,
    unsigned short* __restrict__ out, unsigned short* __restrict__ out_lo,
    const float* __restrict__ x, const float* __restrict__ scale,
    float* __restrict__ xf, unsigned short* __restrict__ xh,
    unsigned short* __restrict__ xl)
{
    if (blockIdx.x < WBLK4) {
        int i = (blockIdx.x * 256 + threadIdx.x) * 4;
        const float* s; int off;
        if      (i <  393216) { s = a0; off = 0;       }
        else if (i <  524288) { s = a1; off = 393216;  }
        else if (i <  917504) { s = a2; off = 524288;  }
        else if (i < 1048576) { s = a3; off = 917504;  }
        else if (i < 1572864) { s = a4; off = 1048576; }
        else                  { s = a5; off = 1572864; }
        float4 v = *(const float4*)(s + (i - off));
        ushort4 h;
        h.x = f2bfu(v.x); h.y = f2bfu(v.y);
        h.z = f2bfu(v.z); h.w = f2bfu(v.w);
        *(ushort4*)(out + i) = h;
        if (i < WL0) {
            ushort4 lo;
            lo.x = f2bfu(v.x - bfu2f(h.x));
            lo.y = f2bfu(v.y - bfu2f(h.y));
            lo.z = f2bfu(v.z - bfu2f(h.z));
            lo.w = f2bfu(v.w - bfu2f(h.w));
            *(ushort4*)(out_lo + i) = lo;
        }
    } else {
        int i = ((blockIdx.x - WBLK4) * 256 + threadIdx.x) * 4;
        int srow = (i >> 8) & (SS - 1);      // constant across the 4-group
        float pos = (float)srow * scale[0];
        float4 v = *(const float4*)(x + i);
        v.x += pos; v.y += pos; v.z += pos; v.w += pos;
        *(float4*)(xf + i) = v;
        ushort4 h;
        h.x = f2bfu(v.x); h.y = f2bfu(v.y);
        h.z = f2bfu(v.z); h.w = f2bfu(v.w);
        *(ushort4*)(xh + i) = h;
        ushort4 lo;
        lo.x = f2bfu(v.x - bfu2f(h.x));
        lo.y = f2bfu(v.y - bfu2f(h.y));
        lo.z = f2bfu(v.z - bfu2f(h.z));
        lo.w = f2bfu(v.w - bfu2f(h.w));
        *(ushort4*)(xl + i) = lo;
    }
}

// ---------------------------------------------------------------------------
// V-epilogue helper: token row + V-column -> VT[b][h][d][s] index
__device__ __forceinline__ size_t vt_index(int row, int col512) {
    int b = row >> 10, s = row & (SS - 1);
    int h = col512 >> 5, d = col512 & (HD - 1);
    return (((size_t)b * HH + h) * HD + d) * SS + s;
}

// ---------------------------------------------------------------------------
// MFMA GEMM: C[M,N] = A[M,K](bf16) @ W[N,K]^T(bf16) + bias(f32)
//            [+gelu] [+resid f32] -> outf (f32) and/or outb (bf16)
// If vth != null (QKV proj): cols >= 512 go transposed to VT[b][h][d][s].
// 64xBN block tile, 256 thr = 4 waves (2x2). BN=64 everywhere:
// N=768 -> 768 blocks = 3/CU even (round-6 win, -12us); N=1024 (W1) ->
// 1024 blocks = 4/CU even (round-8 win). Staged LDS + barriers kept per
// round-3 post-mortem (TLP hides latency at >=2 blk/CU).
#define LDP 40
template<int BN>
__global__ __launch_bounds__(256) void gemm_mfma(
    const unsigned short* __restrict__ A, const unsigned short* __restrict__ W,
    const float* __restrict__ bias, const float* __restrict__ resid,
    float* __restrict__ outf, unsigned short* __restrict__ outb,
    unsigned short* __restrict__ vth,
    int M, int N, int K, int act)
{
    constexpr int NJ = BN / 32;          // col frags per wave: 4 or 2
    __shared__ __align__(16) unsigned short As[64 * LDP];
    __shared__ __align__(16) unsigned short Bs[BN * LDP];
    const int t = threadIdx.x;
    const int lane = t & 63, wave = t >> 6;
    const int wr = wave >> 1, wc = wave & 1;
    const int m0 = blockIdx.y * 64, n0 = blockIdx.x * BN;
    const int sr = t >> 2;
    const int sc = (t & 3) * 8;

    const unsigned short* Ag = A + (size_t)(m0 + sr) * K + sc;
    const unsigned short* Wg = W + (size_t)(n0 + sr) * K + sc;

    f32x4 acc[2][NJ];
    #pragma unroll
    for (int i = 0; i < 2; i++)
        #pragma unroll
        for (int j = 0; j < NJ; j++)
            acc[i][j] = (f32x4){0.f, 0.f, 0.f, 0.f};

    const int lm = lane & 15, lk = (lane >> 4) * 8;

    uint4 a0 = *(const uint4*)(Ag);
    uint4 b0 = *(const uint4*)(Wg);
    uint4 b1;
    if constexpr (BN == 128) b1 = *(const uint4*)(Wg + (size_t)64 * K);

    for (int k0 = 0; k0 < K; k0 += 32) {
        __syncthreads();
        *(uint4*)&As[sr * LDP + sc] = a0;
        *(uint4*)&Bs[sr * LDP + sc] = b0;
        if constexpr (BN == 128) *(uint4*)&Bs[(sr + 64) * LDP + sc] = b1;
        __syncthreads();
        if (k0 + 32 < K) {
            a0 = *(const uint4*)(Ag + k0 + 32);
            b0 = *(const uint4*)(Wg + k0 + 32);
            if constexpr (BN == 128)
                b1 = *(const uint4*)(Wg + (size_t)64 * K + k0 + 32);
        }

        short8 af[2], bf[NJ];
        #pragma unroll
        for (int i = 0; i < 2; i++)
            af[i] = *(const short8*)&As[(wr * 32 + i * 16 + lm) * LDP + lk];
        #pragma unroll
        for (int j = 0; j < NJ; j++)
            bf[j] = *(const short8*)&Bs[(wc * (BN / 2) + j * 16 + lm) * LDP + lk];
        #pragma unroll
        for (int i = 0; i < 2; i++)
            #pragma unroll
            for (int j = 0; j < NJ; j++)
                acc[i][j] = __builtin_amdgcn_mfma_f32_16x16x32_bf16(
                    af[i], bf[j], acc[i][j], 0, 0, 0);
    }

    const int lq = lane >> 4;
    #pragma unroll
    for (int j = 0; j < NJ; j++) {
        int col = n0 + wc * (BN / 2) + j * 16 + lm;
        float bv = bias[col];
        #pragma unroll
        for (int i = 0; i < 2; i++) {
            #pragma unroll
            for (int r = 0; r < 4; r++) {
                int row = m0 + wr * 32 + i * 16 + lq * 4 + r;
                float v = acc[i][j][r] + bv;
                if (act) v = 0.5f * v * (1.0f + erff(v * 0.70710678118654752f));
                if (vth && col >= 2 * DD) {
                    vth[vt_index(row, col - 2 * DD)] = f2bfu(v);
                } else {
                    size_t idx = (size_t)row * N + col;
                    if (resid) v += resid[idx];
                    if (outf) outf[idx] = v;
                    if (outb) outb[idx] = f2bfu(v);
                }
            }
        }
    }
}

// ---------------------------------------------------------------------------
// Full-row GEMM (N=256) + residual [+ LayerNorm] fused epilogue.
// Barrier-free K-loop (PROVEN WIN at 1 block/CU: round-2 -11us). A built in
// LDS once; B wave-private panels via depth-4 register ring.
template<bool COMBINE, bool DOLN, int K>
__global__ __launch_bounds__(256) void gemm_ln(
    const unsigned short* __restrict__ A,
    const float* __restrict__ Of, const float2* __restrict__ Ml,
    const unsigned short* __restrict__ W, const float* __restrict__ bias,
    const float* __restrict__ resid,
    const float* __restrict__ g, const float* __restrict__ bt,
    float* __restrict__ outf, unsigned short* __restrict__ outb)
{
    constexpr int LDA = K + 8;       // row stride in shorts (16B-aligned rows)
    constexpr int NS  = K / 32;      // number of 32-wide K steps
    __shared__ __align__(16) unsigned short As[16 * LDA];
    __shared__ float rsum[4][16];
    __shared__ float rsum2[4][16];
    const int t = threadIdx.x;
    const int lane = t & 63, wave = t >> 6;
    const int m0 = blockIdx.x * 16;
    const int lm = lane & 15, quad = lane >> 4;

    // ---- issue first B-ring loads before A-staging so they overlap it
    const unsigned short* Wp = W + (size_t)(wave * 64 + lm) * K + quad * 8;
    short8 bf[4][4];
    #pragma unroll
    for (int s = 0; s < 4; s++)
        #pragma unroll
        for (int j = 0; j < 4; j++)
            bf[s][j] = *(const short8*)(Wp + (size_t)(j * 16) * K + s * 32);

    // ---- Phase 1: build As[16][K] once (all 256 threads participate)
    if (COMBINE) {
        // K == 256 here. thread -> (row, 16-col group); 32 cols per head.
        const int row = t >> 4, cg = t & 15;
        const int token = m0 + row;
        const int h = cg >> 1;
        float2 ml[NSEG];
        float M = -1e30f;
        #pragma unroll
        for (int s = 0; s < NSEG; s++) {
            ml[s] = Ml[((size_t)s * NTOK + token) * HH + h];
            M = fmaxf(M, ml[s].x);
        }
        float wgt[NSEG]; float denom = 0.f;
        #pragma unroll
        for (int s = 0; s < NSEG; s++) {
            wgt[s] = __expf(ml[s].x - M);
            denom += ml[s].y * wgt[s];
        }
        const float inv = 1.0f / denom;
        float a16[16];
        #pragma unroll
        for (int c = 0; c < 16; c++) a16[c] = 0.f;
        #pragma unroll
        for (int s = 0; s < NSEG; s++) {
            const float* p = Of + ((size_t)s * NTOK + token) * DD + cg * 16;
            #pragma unroll
            for (int c4 = 0; c4 < 4; c4++) {
                float4 x = *(const float4*)(p + c4 * 4);
                a16[c4 * 4 + 0] += x.x * wgt[s];
                a16[c4 * 4 + 1] += x.y * wgt[s];
                a16[c4 * 4 + 2] += x.z * wgt[s];
                a16[c4 * 4 + 3] += x.w * wgt[s];
            }
        }
        __align__(16) unsigned short ab[16];
        #pragma unroll
        for (int c = 0; c < 16; c++) ab[c] = f2bfu(a16[c] * inv);
        *(uint4*)&As[row * LDA + cg * 16]     = *(uint4*)&ab[0];
        *(uint4*)&As[row * LDA + cg * 16 + 8] = *(uint4*)&ab[8];
    } else {
        #pragma unroll
        for (int u = t; u < 16 * (K / 8); u += 256) {
            int row = u / (K / 8), cg = u % (K / 8);   // pow2 -> shifts
            *(uint4*)&As[row * LDA + cg * 8] =
                *(const uint4*)(A + (size_t)(m0 + row) * K + cg * 8);
        }
    }
    __syncthreads();

    // ---- Phase 2: barrier-free K loop, depth-4 register ring on B
    f32x4 acc[4];
    #pragma unroll
    for (int j = 0; j < 4; j++) acc[j] = (f32x4){0.f, 0.f, 0.f, 0.f};

    #pragma unroll
    for (int k = 0; k < NS; k++) {
        const int r4 = k & 3;
        short8 af = *(const short8*)&As[lm * LDA + k * 32 + quad * 8];
        #pragma unroll
        for (int j = 0; j < 4; j++)
            acc[j] = __builtin_amdgcn_mfma_f32_16x16x32_bf16(
                af, bf[r4][j], acc[j], 0, 0, 0);
        if (k + 4 < NS) {
            #pragma unroll
            for (int j = 0; j < 4; j++)
                bf[r4][j] = *(const short8*)(Wp + (size_t)(j * 16) * K
                                             + (k + 4) * 32);
        }
    }

    // ---- epilogue: bias + resid [+ per-row LayerNorm].
    // Wave w holds rows (quad*4+r) x cols (64w + 16j + lm).
    #pragma unroll
    for (int j = 0; j < 4; j++) {
        int col = wave * 64 + j * 16 + lm;
        float bv = bias[col];
        #pragma unroll
        for (int r = 0; r < 4; r++) {
            int row = m0 + quad * 4 + r;
            acc[j][r] += bv + resid[(size_t)row * DD + col];
        }
    }
    if (!DOLN) {
        #pragma unroll
        for (int j = 0; j < 4; j++) {
            int col = wave * 64 + j * 16 + lm;
            #pragma unroll
            for (int r = 0; r < 4; r++) {
                int row = m0 + quad * 4 + r;
                size_t idx = (size_t)row * DD + col;
                if (outf) outf[idx] = acc[j][r];
                if (outb) outb[idx] = f2bfu(acc[j][r]);
            }
        }
        return;
    }
    #pragma unroll
    for (int r = 0; r < 4; r++) {
        float s = 0.f;
        #pragma unroll
        for (int j = 0; j < 4; j++) s += acc[j][r];
        s += __shfl_xor(s, 1, 64); s += __shfl_xor(s, 2, 64);
        s += __shfl_xor(s, 4, 64); s += __shfl_xor(s, 8, 64);
        if (lm == 0) rsum[wave][quad * 4 + r] = s;
    }
    __syncthreads();
    float mean_[4];
    #pragma unroll
    for (int r = 0; r < 4; r++) {
        int ri = quad * 4 + r;
        mean_[r] = (rsum[0][ri] + rsum[1][ri] + rsum[2][ri] + rsum[3][ri])
                 * (1.0f / 256.0f);
    }
    #pragma unroll
    for (int r = 0; r < 4; r++) {
        float s2 = 0.f;
        #pragma unroll
        for (int j = 0; j < 4; j++) {
            float d = acc[j][r] - mean_[r];
            s2 += d * d;
        }
        s2 += __shfl_xor(s2, 1, 64); s2 += __shfl_xor(s2, 2, 64);
        s2 += __shfl_xor(s2, 4, 64); s2 += __shfl_xor(s2, 8, 64);
        if (lm == 0) rsum2[wave][quad * 4 + r] = s2;
    }
    __syncthreads();
    float rstd[4];
    #pragma unroll
    for (int r = 0; r < 4; r++) {
        int ri = quad * 4 + r;
        rstd[r] = rsqrtf((rsum2[0][ri] + rsum2[1][ri] + rsum2[2][ri] + rsum2[3][ri])
                         * (1.0f / 256.0f) + 1e-5f);
    }
    #pragma unroll
    for (int j = 0; j < 4; j++) {
        int col = wave * 64 + j * 16 + lm;
        float gv = g[col], bv2 = bt[col];
        #pragma unroll
        for (int r = 0; r < 4; r++) {
            int row = m0 + quad * 4 + r;
            float ov = (acc[j][r] - mean_[r]) * rstd[r] * gv + bv2;
            size_t idx = (size_t)row * DD + col;
            if (outf) outf[idx] = ov;
            if (outb) outb[idx] = f2bfu(ov);
        }
    }
}

// ---------------------------------------------------------------------------
// Split (hi/lo bf16 ~ fp32) MFMA GEMM for the layer-0 QKV projection.
// Q,K -> packed hi/lo; V -> transposed VT (hi only). Register-prefetched.
// 64x64 tile -> 768 blocks = 3/CU even (round-6 win).
__global__ __launch_bounds__(256) void gemm_mfma_split(
    const unsigned short* __restrict__ Ah, const unsigned short* __restrict__ Al,
    const unsigned short* __restrict__ Wh, const unsigned short* __restrict__ Wl,
    const float* __restrict__ bias,
    unsigned short* __restrict__ outh, unsigned short* __restrict__ outl,
    unsigned short* __restrict__ vth,
    int M, int N, int K)
{
    __shared__ __align__(16) unsigned short Ash[64 * LDP];
    __shared__ __align__(16) unsigned short Asl[64 * LDP];
    __shared__ __align__(16) unsigned short Bsh[64 * LDP];
    __shared__ __align__(16) unsigned short Bsl[64 * LDP];
    const int t = threadIdx.x;
    const int lane = t & 63, wave = t >> 6;
    const int wr = wave >> 1, wc = wave & 1;
    const int m0 = blockIdx.y * 64, n0 = blockIdx.x * 64;
    const int sr = t >> 2;
    const int sc = (t & 3) * 8;

    const size_t oA = (size_t)(m0 + sr) * K + sc;
    const size_t oW = (size_t)(n0 + sr) * K + sc;

    f32x4 acc[2][2];
    #pragma unroll
    for (int i = 0; i < 2; i++)
        #pragma unroll
        for (int j = 0; j < 2; j++)
            acc[i][j] = (f32x4){0.f, 0.f, 0.f, 0.f};

    const int lm = lane & 15, lk = (lane >> 4) * 8;

    uint4 ah0 = *(const uint4*)(Ah + oA);
    uint4 al0 = *(const uint4*)(Al + oA);
    uint4 bh0 = *(const uint4*)(Wh + oW);
    uint4 bl0 = *(const uint4*)(Wl + oW);

    for (int k0 = 0; k0 < K; k0 += 32) {
        __syncthreads();
        *(uint4*)&Ash[sr * LDP + sc] = ah0;
        *(uint4*)&Asl[sr * LDP + sc] = al0;
        *(uint4*)&Bsh[sr * LDP + sc] = bh0;
        *(uint4*)&Bsl[sr * LDP + sc] = bl0;
        __syncthreads();
        if (k0 + 32 < K) {
            ah0 = *(const uint4*)(Ah + oA + k0 + 32);
            al0 = *(const uint4*)(Al + oA + k0 + 32);
            bh0 = *(const uint4*)(Wh + oW + k0 + 32);
            bl0 = *(const uint4*)(Wl + oW + k0 + 32);
        }

        short8 afh[2], afl[2], bfh[2], bfl[2];
        #pragma unroll
        for (int i = 0; i < 2; i++) {
            afh[i] = *(const short8*)&Ash[(wr * 32 + i * 16 + lm) * LDP + lk];
            afl[i] = *(const short8*)&Asl[(wr * 32 + i * 16 + lm) * LDP + lk];
        }
        #pragma unroll
        for (int j = 0; j < 2; j++) {
            bfh[j] = *(const short8*)&Bsh[(wc * 32 + j * 16 + lm) * LDP + lk];
            bfl[j] = *(const short8*)&Bsl[(wc * 32 + j * 16 + lm) * LDP + lk];
        }
        #pragma unroll
        for (int i = 0; i < 2; i++)
            #pragma unroll
            for (int j = 0; j < 2; j++) {
                acc[i][j] = __builtin_amdgcn_mfma_f32_16x16x32_bf16(
                    afl[i], bfh[j], acc[i][j], 0, 0, 0);
                acc[i][j] = __builtin_amdgcn_mfma_f32_16x16x32_bf16(
                    afh[i], bfl[j], acc[i][j], 0, 0, 0);
                acc[i][j] = __builtin_amdgcn_mfma_f32_16x16x32_bf16(
                    afh[i], bfh[j], acc[i][j], 0, 0, 0);
            }
    }

    const int lq = lane >> 4;
    #pragma unroll
    for (int j = 0; j < 2; j++) {
        int col = n0 + wc * 32 + j * 16 + lm;
        float bv = bias[col];
        #pragma unroll
        for (int i = 0; i < 2; i++) {
            #pragma unroll
            for (int r = 0; r < 4; r++) {
                int row = m0 + wr * 32 + i * 16 + lq * 4 + r;
                float v = acc[i][j][r] + bv;
                unsigned short h = f2bfu(v);
                if (col >= 2 * DD) {
                    vth[vt_index(row, col - 2 * DD)] = h;
                } else {
                    size_t idx = (size_t)row * N + col;
                    outh[idx] = h;
                    outl[idx] = f2bfu(v - bfu2f(h));
                }
            }
        }
    }
}

// ---------------------------------------------------------------------------
// MFMA flash attention, SPLIT (hi/lo) scores with ONLINE softmax — layer-0
// full attention only. V hi-only. Swapped QK^T (round-5 win). Split-K NSEG=4
// (2048 blocks = 8/CU — round-7 post-mortem: this TLP is load-bearing).
__global__ __launch_bounds__(256) void attn_split(
    const unsigned short* __restrict__ qkvh,
    const unsigned short* __restrict__ qkvl,
    const unsigned short* __restrict__ vth,
    float* __restrict__ Of, float2* __restrict__ Ml)
{
    __shared__ __align__(16) unsigned short Ks [64 * 40];
    __shared__ __align__(16) unsigned short Vt [32 * 72];
    __shared__ __align__(16) unsigned short Ps [64 * 72];
    __shared__ __align__(16) unsigned short Ksl[64 * 40];

    const int t = threadIdx.x;
    const int wave = t >> 6, lane = t & 63;
    const int lm = lane & 15, quad = lane >> 4;
    const int i0 = blockIdx.x * 64, h = blockIdx.y;
    const int z = blockIdx.z;
    const int b = z >> 2, seg = z & (NSEG - 1);
    const int sr = t >> 2, sc8 = (t & 3) * 8;
    const int vd = t >> 3, vs8 = (t & 7) * 8;

    const size_t qoff = ((size_t)(b * SS) + i0 + 16 * wave + lm) * D3 + h * HD + quad * 8;
    short8 qh = *(const short8*)(qkvh + qoff);
    short8 ql = *(const short8*)(qkvl + qoff);

    const unsigned short* Kg  = qkvh + (size_t)(b * SS) * D3 + DD + h * HD;
    const unsigned short* Klg = qkvl + (size_t)(b * SS) * D3 + DD + h * HD;
    const unsigned short* Vg  = vth + ((size_t)b * HH + h) * HD * SS;

    float m = -1e30f, l = 0.f;
    f32x4 o[2];
    o[0] = (f32x4){0.f, 0.f, 0.f, 0.f};
    o[1] = (f32x4){0.f, 0.f, 0.f, 0.f};

    const int per = (SS / 64) / NSEG;
    const int s0 = seg * per, s1 = s0 + per - 1;
    const float scl = 0.17677669529663688f;  // 1/sqrt(32)

    short8 kreg  = *(const short8*)(Kg  + (size_t)(s0 * 64 + sr) * D3 + sc8);
    short8 kregl = *(const short8*)(Klg + (size_t)(s0 * 64 + sr) * D3 + sc8);
    short8 vreg  = *(const short8*)(Vg  + (size_t)vd * SS + s0 * 64 + vs8);

    for (int kt = s0; kt <= s1; kt++) {
        const int k0 = kt * 64;
        __syncthreads();
        *(short8*)&Ks [sr * 40 + sc8] = kreg;
        *(short8*)&Ksl[sr * 40 + sc8] = kregl;
        *(short8*)&Vt [vd * 72 + vs8] = vreg;
        __syncthreads();
        if (kt < s1) {
            kreg  = *(const short8*)(Kg  + (size_t)(k0 + 64 + sr) * D3 + sc8);
            kregl = *(const short8*)(Klg + (size_t)(k0 + 64 + sr) * D3 + sc8);
            vreg  = *(const short8*)(Vg  + (size_t)vd * SS + k0 + 64 + vs8);
        }

        // scores: vs[cb][r] = S[k = 16cb + quad*4 + r][q = lm] * scl
        float vs[4][4];
        #pragma unroll
        for (int cb = 0; cb < 4; cb++) {
            short8 kf  = *(const short8*)&Ks [(16 * cb + lm) * 40 + quad * 8];
            short8 kfl = *(const short8*)&Ksl[(16 * cb + lm) * 40 + quad * 8];
            f32x4 a = (f32x4){0.f, 0.f, 0.f, 0.f};
            a = __builtin_amdgcn_mfma_f32_16x16x32_bf16(kf,  ql, a, 0, 0, 0);
            a = __builtin_amdgcn_mfma_f32_16x16x32_bf16(kfl, qh, a, 0, 0, 0);
            a = __builtin_amdgcn_mfma_f32_16x16x32_bf16(kf,  qh, a, 0, 0, 0);
            #pragma unroll
            for (int r = 0; r < 4; r++) vs[cb][r] = a[r] * scl;
        }

        // row max: in-lane tree over 16 + cross-quad combine
        float tm = fmaxf(fmaxf(vs[0][0], vs[0][1]), fmaxf(vs[0][2], vs[0][3]));
        #pragma unroll
        for (int cb = 1; cb < 4; cb++)
            tm = fmaxf(tm, fmaxf(fmaxf(vs[cb][0], vs[cb][1]),
                                 fmaxf(vs[cb][2], vs[cb][3])));
        tm = fmaxf(tm, __shfl_xor(tm, 16, 64));
        tm = fmaxf(tm, __shfl_xor(tm, 32, 64));
        float mn = fmaxf(m, tm);
        float alpha = __expf(m - mn);
        m = mn;

        // p = exp(s - mn), in-lane partial sum, packed b64 store of P^T
        float ps = 0.f;
        #pragma unroll
        for (int cb = 0; cb < 4; cb++) {
            float p0 = __expf(vs[cb][0] - mn), p1 = __expf(vs[cb][1] - mn);
            float p2 = __expf(vs[cb][2] - mn), p3 = __expf(vs[cb][3] - mn);
            ps += (p0 + p1) + (p2 + p3);
            uint2 pk;
            pk.x = (unsigned)f2bfu(p0) | ((unsigned)f2bfu(p1) << 16);
            pk.y = (unsigned)f2bfu(p2) | ((unsigned)f2bfu(p3) << 16);
            *(uint2*)&Ps[(16 * wave + lm) * 72 + 16 * cb + quad * 4] = pk;
        }
        ps += __shfl_xor(ps, 16, 64);
        ps += __shfl_xor(ps, 32, 64);
        l = l * alpha + ps;

        // redistribute alpha from q=lm layout to o row-layout (q=quad*4+r)
        float ar[4];
        #pragma unroll
        for (int r = 0; r < 4; r++) ar[r] = __shfl(alpha, quad * 4 + r, 64);
        #pragma unroll
        for (int r = 0; r < 4; r++) { o[0][r] *= ar[r]; o[1][r] *= ar[r]; }

        #pragma unroll
        for (int kc = 0; kc < 2; kc++) {
            short8 pf = *(const short8*)&Ps[(16 * wave + lm) * 72 + 32 * kc + quad * 8];
            #pragma unroll
            for (int nh = 0; nh < 2; nh++) {
                short8 vf = *(const short8*)&Vt[(16 * nh + lm) * 72 + 32 * kc + quad * 8];
                o[nh] = __builtin_amdgcn_mfma_f32_16x16x32_bf16(pf, vf, o[nh], 0, 0, 0);
            }
        }
    }

    #pragma unroll
    for (int r = 0; r < 4; r++) {
        int row = i0 + 16 * wave + quad * 4 + r;
        size_t base = ((size_t)seg * NTOK + b * SS + row) * DD + h * HD + lm;
        Of[base]      = o[0][r];
        Of[base + 16] = o[1][r];
    }
    if (quad == 0)
        Ml[((size_t)seg * NTOK + b * SS + i0 + 16 * wave + lm) * HH + h] =
            make_float2(m, l);
}

// ---------------------------------------------------------------------------
// MFMA flash attention, FIXED-MAX softmax (post-LN inputs: scores O(1)).
// nseg==1: normalized bf16 out. nseg>1: f32 unnormalized partials + (32,l).
// Swapped QK^T (round-5) — zero in-loop shfl; l reduced once at the end.
__global__ __launch_bounds__(256) void attn_fixed(
    const unsigned short* __restrict__ qkvh,
    const unsigned short* __restrict__ vth,
    unsigned short* __restrict__ outb,
    float* __restrict__ Of, float2* __restrict__ Ml,
    int win, int nseg)
{
    __shared__ __align__(16) unsigned short Ks[64 * 40];
    __shared__ __align__(16) unsigned short Vt[32 * 72];
    __shared__ __align__(16) unsigned short Ps[64 * 72];

    const int t = threadIdx.x;
    const int wave = t >> 6, lane = t & 63;
    const int lm = lane & 15, quad = lane >> 4;
    const int i0 = blockIdx.x * 64, h = blockIdx.y;
    const int z = blockIdx.z;
    const int b = z / nseg, seg = z - b * nseg;
    const int sr = t >> 2, sc8 = (t & 3) * 8;
    const int vd = t >> 3, vs8 = (t & 7) * 8;

    const size_t qoff = ((size_t)(b * SS) + i0 + 16 * wave + lm) * D3 + h * HD + quad * 8;
    short8 qh = *(const short8*)(qkvh + qoff);

    const unsigned short* Kg = qkvh + (size_t)(b * SS) * D3 + DD + h * HD;
    const unsigned short* Vg = vth + ((size_t)b * HH + h) * HD * SS;

    float l = 0.f;               // per-lane partial sum for q = lm
    f32x4 o[2];
    o[0] = (f32x4){0.f, 0.f, 0.f, 0.f};
    o[1] = (f32x4){0.f, 0.f, 0.f, 0.f};

    int t0 = 0, t1 = SS / 64 - 1;
    const bool masked = (win < SS);
    if (masked) {
        t0 = (i0 - win) >> 6;        if (t0 < 0) t0 = 0;
        t1 = (i0 + 63 + win) >> 6;   if (t1 > SS / 64 - 1) t1 = SS / 64 - 1;
    }
    const int per = (t1 - t0 + nseg) / nseg;
    const int s0 = t0 + seg * per;
    const int s1 = (s0 + per - 1 < t1) ? (s0 + per - 1) : t1;
    const float scl = 0.17677669529663688f;  // 1/sqrt(32)
    const float M0 = 32.0f;                   // fixed softmax shift

    const int qrow = i0 + 16 * wave + lm;     // this lane's q (swapped layout)

    short8 kreg = *(const short8*)(Kg + (size_t)(s0 * 64 + sr) * D3 + sc8);
    short8 vreg = *(const short8*)(Vg + (size_t)vd * SS + s0 * 64 + vs8);

    for (int kt = s0; kt <= s1; kt++) {
        const int k0 = kt * 64;
        __syncthreads();
        *(short8*)&Ks[sr * 40 + sc8] = kreg;
        *(short8*)&Vt[vd * 72 + vs8] = vreg;
        __syncthreads();
        if (kt < s1) {
            kreg = *(const short8*)(Kg + (size_t)(k0 + 64 + sr) * D3 + sc8);
            vreg = *(const short8*)(Vg + (size_t)vd * SS + k0 + 64 + vs8);
        }

        #pragma unroll
        for (int cb = 0; cb < 4; cb++) {
            short8 kf = *(const short8*)&Ks[(16 * cb + lm) * 40 + quad * 8];
            f32x4 a = (f32x4){0.f, 0.f, 0.f, 0.f};
            a = __builtin_amdgcn_mfma_f32_16x16x32_bf16(kf, qh, a, 0, 0, 0);
            // a[r] = S[k = k0 + 16cb + quad*4 + r][q = qrow]
            float p[4];
            #pragma unroll
            for (int r = 0; r < 4; r++) {
                float v = a[r] * scl;
                if (masked) {
                    int di = qrow - (k0 + 16 * cb + quad * 4 + r);
                    if (di > win || di < -win) v = -1e30f;
                }
                p[r] = __expf(v - M0);
            }
            l += (p[0] + p[1]) + (p[2] + p[3]);
            uint2 pk;
            pk.x = (unsigned)f2bfu(p[0]) | ((unsigned)f2bfu(p[1]) << 16);
            pk.y = (unsigned)f2bfu(p[2]) | ((unsigned)f2bfu(p[3]) << 16);
            *(uint2*)&Ps[(16 * wave + lm) * 72 + 16 * cb + quad * 4] = pk;
        }
        // Ps region is wave-private — no barrier needed

        #pragma unroll
        for (int kc = 0; kc < 2; kc++) {
            short8 pf = *(const short8*)&Ps[(16 * wave + lm) * 72 + 32 * kc + quad * 8];
            #pragma unroll
            for (int nh = 0; nh < 2; nh++) {
                short8 vf = *(const short8*)&Vt[(16 * nh + lm) * 72 + 32 * kc + quad * 8];
                o[nh] = __builtin_amdgcn_mfma_f32_16x16x32_bf16(pf, vf, o[nh], 0, 0, 0);
            }
        }
    }

    // full row sum for q = lm: combine the 4 quad partials
    l += __shfl_xor(l, 16, 64);
    l += __shfl_xor(l, 32, 64);

    if (nseg == 1) {
        // redistribute l from q=lm layout to o row-layout (q = quad*4+r)
        #pragma unroll
        for (int r = 0; r < 4; r++) {
            float lr = __shfl(l, quad * 4 + r, 64);
            float invl = 1.0f / lr;
            size_t base = ((size_t)(b * SS) + i0 + 16 * wave + quad * 4 + r) * DD + h * HD + lm;
            outb[base]      = f2bfu(o[0][r] * invl);
            outb[base + 16] = f2bfu(o[1][r] * invl);
        }
    } else {
        #pragma unroll
        for (int r = 0; r < 4; r++) {
            int row = i0 + 16 * wave + quad * 4 + r;
            size_t base = ((size_t)seg * NTOK + b * SS + row) * DD + h * HD + lm;
            Of[base]      = o[0][r];
            Of[base + 16] = o[1][r];
        }
        if (quad == 0)
            Ml[((size_t)seg * NTOK + b * SS + i0 + 16 * wave + lm) * HH + h] =
                make_float2(M0, l);
    }
}

// ---------------------------------------------------------------------------
extern "C" void kernel_launch(void* const* d_in, const int* in_sizes, int n_in,
                              void* d_out, int out_size, void* d_ws, size_t ws_size,
                              hipStream_t stream)
{
    const float* xin   = (const float*)d_in[0];
    const float* scale = (const float*)d_in[1];
    const float* Win_a = (const float*)d_in[2];
    const float* bin_a = (const float*)d_in[3];
    const float* Wout_a= (const float*)d_in[4];
    const float* bout_a= (const float*)d_in[5];
    const float* Win_e = (const float*)d_in[6];
    const float* bin_e = (const float*)d_in[7];
    const float* Wout_e= (const float*)d_in[8];
    const float* bout_e= (const float*)d_in[9];
    const float* ln1_g = (const float*)d_in[10];
    const float* ln1_b = (const float*)d_in[11];
    const float* ln2_g = (const float*)d_in[12];
    const float* ln2_b = (const float*)d_in[13];
    const float* W1    = (const float*)d_in[14];
    const float* b1    = (const float*)d_in[15];
    const float* W2    = (const float*)d_in[16];
    const float* b2    = (const float*)d_in[17];
    const float* lnf_g = (const float*)d_in[18];
    const float* lnf_b = (const float*)d_in[19];

    char* ws = (char*)d_ws;
    float* X    = (float*)ws;                     ws += (size_t)NTOK * DD * 4;
    float* X2   = (float*)ws;                     ws += (size_t)NTOK * DD * 4;
    unsigned short* Xb   = (unsigned short*)ws;   ws += (size_t)NTOK * DD * 2;
    unsigned short* Xlb  = (unsigned short*)ws;   ws += (size_t)NTOK * DD * 2;
    unsigned short* X2b  = (unsigned short*)ws;   ws += (size_t)NTOK * DD * 2;
    unsigned short* ATb  = (unsigned short*)ws;   ws += (size_t)NTOK * DD * 2;
    unsigned short* QKVb = (unsigned short*)ws;   ws += (size_t)NTOK * D3 * 2;
    unsigned short* QKVl = (unsigned short*)ws;   ws += (size_t)NTOK * D3 * 2;
    unsigned short* VTh  = (unsigned short*)ws;   ws += (size_t)NTOK * DD * 2;
    unsigned short* HMLb = (unsigned short*)ws;   ws += (size_t)NTOK * MLP * 2;
    unsigned short* Wb   = (unsigned short*)ws;   ws += (size_t)W_TOT * 2;
    unsigned short* Wl0  = (unsigned short*)ws;   ws += (size_t)WL0 * 2;
    float2* Ml           = (float2*)ws;           ws += (size_t)NSEG * NTOK * HH * 8;
    float* Of            = (float*)ws;            ws += (size_t)NSEG * NTOK * DD * 4;

    unsigned short* WinA_b  = Wb + 0;
    unsigned short* WoutA_b = Wb + 393216;
    unsigned short* WinE_b  = Wb + 524288;
    unsigned short* WoutE_b = Wb + 917504;
    unsigned short* W1_b    = Wb + 1048576;
    unsigned short* W2_b    = Wb + 1572864;

    prep_kernel<<<WBLK4 + PBLK4, 256, 0, stream>>>(
        Win_a, Wout_a, Win_e, Wout_e, W1, W2, Wb, Wl0,
        xin, scale, X, Xb, Xlb);

    float* cur = X;            float* oth = X2;
    unsigned short* curb = Xb; unsigned short* othb = X2b;

    for (int l = 0; l < 2; l++) {
        // --- full self-attention (split-K NSEG, combine+LN fused into Wout)
        if (l == 0) {
            gemm_mfma_split<<<dim3(D3 / 64, NTOK / 64), 256, 0, stream>>>(
                Xb, Xlb, WinA_b, Wl0, bin_a, QKVb, QKVl, VTh, NTOK, D3, DD);
            attn_split<<<dim3(SS / 64, HH, BB * NSEG), 256, 0, stream>>>(
                QKVb, QKVl, VTh, Of, Ml);
        } else {
            gemm_mfma<64><<<dim3(D3 / 64, NTOK / 64), 256, 0, stream>>>(
                curb, WinA_b + (size_t)l * D3 * DD, bin_a + (size_t)l * D3,
                nullptr, nullptr, QKVb, VTh, NTOK, D3, DD, 0);
            attn_fixed<<<dim3(SS / 64, HH, BB * NSEG), 256, 0, stream>>>(
                QKVb, VTh, nullptr, Of, Ml, 1 << 28, NSEG);
        }
        gemm_ln<true, true, DD><<<NTOK / 16, 256, 0, stream>>>(
            nullptr, Of, Ml, WoutA_b + (size_t)l * DD * DD,
            bout_a + (size_t)l * DD, cur,
            ln1_g + l * DD, ln1_b + l * DD, oth, othb);

        // --- banded self-attention (|i-j| <= 64), LN fused into Wout
        gemm_mfma<64><<<dim3(D3 / 64, NTOK / 64), 256, 0, stream>>>(
            othb, WinE_b + (size_t)l * D3 * DD, bin_e + (size_t)l * D3,
            nullptr, nullptr, QKVb, VTh, NTOK, D3, DD, 0);
        attn_fixed<<<dim3(SS / 64, HH, BB), 256, 0, stream>>>(
            QKVb, VTh, ATb, nullptr, nullptr, 64, 1);
        gemm_ln<false, true, DD><<<NTOK / 16, 256, 0, stream>>>(
            ATb, nullptr, nullptr, WoutE_b + (size_t)l * DD * DD,
            bout_e + (size_t)l * DD, oth,
            ln2_g + l * DD, ln2_b + l * DD, cur, curb);
        // attended now in cur/curb

        // --- MLP with exact gelu; layer-1's W2 fuses the final LayerNorm
        gemm_mfma<64><<<dim3(MLP / 64, NTOK / 64), 256, 0, stream>>>(
            curb, W1_b + (size_t)l * MLP * DD, b1 + (size_t)l * MLP,
            nullptr, nullptr, HMLb, nullptr, NTOK, MLP, DD, 1);
        if (l == 0) {
            // full-row no-LN GEMM: grid 256 (full machine)
            gemm_ln<false, false, MLP><<<NTOK / 16, 256, 0, stream>>>(
                HMLb, nullptr, nullptr, W2_b + (size_t)l * DD * MLP,
                b2 + (size_t)l * DD, cur,
                nullptr, nullptr, oth, othb);
            float* tf = cur; cur = oth; oth = tf;
            unsigned short* tb = curb; curb = othb; othb = tb;
        } else {
            gemm_ln<false, true, MLP><<<NTOK / 16, 256, 0, stream>>>(
                HMLb, nullptr, nullptr, W2_b + (size_t)l * DD * MLP,
                b2 + (size_t)l * DD, cur,
                lnf_g, lnf_b, (float*)d_out, nullptr);
        }
    }
}

// Round 10
// 293.754 us; speedup vs baseline: 1.0087x; 1.0087x over previous
//
#include <hip/hip_runtime.h>
#include <math.h>

// Problem constants
#define BB 4
#define SS 1024
#define DD 256
#define HH 8
#define HD 32
#define D3 768
#define MLP 1024
#define NTOK (BB * SS)   // 4096
#define NSEG 4           // split-K segments for full attention (load-bearing
                         // for TLP — round-7 post-mortem: nseg=1 regressed)

typedef __attribute__((ext_vector_type(8))) short short8;
typedef __attribute__((ext_vector_type(4))) float f32x4;

__device__ __forceinline__ unsigned short f2bfu(float f) {
    union { float f; unsigned i; } u; u.f = f;
    unsigned r = u.i + 0x7fffu + ((u.i >> 16) & 1u);   // RNE
    return (unsigned short)(r >> 16);
}
__device__ __forceinline__ float bfu2f(unsigned short h) {
    union { unsigned i; float f; } u; u.i = ((unsigned)h) << 16; return u.f;
}

// ---------------------------------------------------------------------------
// Fused prep: weights fp32->bf16 (+lo for Win_a layer 0)  AND  x+pos encode.
// 4 elems/thread (float4/ushort4) — round-9: neutral vs scalar (BW-bound
// either way) but kept for the smaller grid. Bit-exact per element.
#define W_TOT 2097152
#define WL0   196608   // 768*256 = Win_a layer 0
#define WBLK4 (W_TOT / 1024)          // 2048 weight blocks (4 elems/thread)
#define PBLK4 (NTOK * DD / 1024)      // 1024 pos blocks
__global__ __launch_bounds__(256) void prep_kernel(
    const float* __restrict__ a0, const float* __restrict__ a1,
    const float* __restrict__ a2, const float* __restrict__ a3,
    const float* __restrict__ a4, const float* __restrict__ a5,
    unsigned short* __restrict__ out, unsigned short* __restrict__ out_lo,
    const float* __restrict__ x, const float* __restrict__ scale,
    float* __restrict__ xf, unsigned short* __restrict__ xh,
    unsigned short* __restrict__ xl)
{
    if (blockIdx.x < WBLK4) {
        int i = (blockIdx.x * 256 + threadIdx.x) * 4;
        const float* s; int off;
        if      (i <  393216) { s = a0; off = 0;       }
        else if (i <  524288) { s = a1; off = 393216;  }
        else if (i <  917504) { s = a2; off = 524288;  }
        else if (i < 1048576) { s = a3; off = 917504;  }
        else if (i < 1572864) { s = a4; off = 1048576; }
        else                  { s = a5; off = 1572864; }
        float4 v = *(const float4*)(s + (i - off));
        ushort4 h;
        h.x = f2bfu(v.x); h.y = f2bfu(v.y);
        h.z = f2bfu(v.z); h.w = f2bfu(v.w);
        *(ushort4*)(out + i) = h;
        if (i < WL0) {
            ushort4 lo;
            lo.x = f2bfu(v.x - bfu2f(h.x));
            lo.y = f2bfu(v.y - bfu2f(h.y));
            lo.z = f2bfu(v.z - bfu2f(h.z));
            lo.w = f2bfu(v.w - bfu2f(h.w));
            *(ushort4*)(out_lo + i) = lo;
        }
    } else {
        int i = ((blockIdx.x - WBLK4) * 256 + threadIdx.x) * 4;
        int srow = (i >> 8) & (SS - 1);      // constant across the 4-group
        float pos = (float)srow * scale[0];
        float4 v = *(const float4*)(x + i);
        v.x += pos; v.y += pos; v.z += pos; v.w += pos;
        *(float4*)(xf + i) = v;
        ushort4 h;
        h.x = f2bfu(v.x); h.y = f2bfu(v.y);
        h.z = f2bfu(v.z); h.w = f2bfu(v.w);
        *(ushort4*)(xh + i) = h;
        ushort4 lo;
        lo.x = f2bfu(v.x - bfu2f(h.x));
        lo.y = f2bfu(v.y - bfu2f(h.y));
        lo.z = f2bfu(v.z - bfu2f(h.z));
        lo.w = f2bfu(v.w - bfu2f(h.w));
        *(ushort4*)(xl + i) = lo;
    }
}

// ---------------------------------------------------------------------------
// V-epilogue helper: token row + V-column -> VT[b][h][d][s] index
__device__ __forceinline__ size_t vt_index(int row, int col512) {
    int b = row >> 10, s = row & (SS - 1);
    int h = col512 >> 5, d = col512 & (HD - 1);
    return (((size_t)b * HH + h) * HD + d) * SS + s;
}

// ---------------------------------------------------------------------------
// MFMA GEMM: C[M,N] = A[M,K](bf16) @ W[N,K]^T(bf16) + bias(f32)
//            [+gelu] [+resid f32] -> outf (f32) and/or outb (bf16)
// If vth != null (QKV proj): cols >= 512 go transposed to VT[b][h][d][s].
// 64xBN block tile, 256 thr = 4 waves (2x2). BN=64 everywhere:
// N=768 -> 768 blocks = 3/CU even (round-6 win, -12us); N=1024 (W1) ->
// 1024 blocks = 4/CU even (round-8 win). Staged LDS + barriers kept per
// round-3 post-mortem (TLP hides latency at >=2 blk/CU).
#define LDP 40
template<int BN>
__global__ __launch_bounds__(256) void gemm_mfma(
    const unsigned short* __restrict__ A, const unsigned short* __restrict__ W,
    const float* __restrict__ bias, const float* __restrict__ resid,
    float* __restrict__ outf, unsigned short* __restrict__ outb,
    unsigned short* __restrict__ vth,
    int M, int N, int K, int act)
{
    constexpr int NJ = BN / 32;          // col frags per wave: 4 or 2
    __shared__ __align__(16) unsigned short As[64 * LDP];
    __shared__ __align__(16) unsigned short Bs[BN * LDP];
    const int t = threadIdx.x;
    const int lane = t & 63, wave = t >> 6;
    const int wr = wave >> 1, wc = wave & 1;
    const int m0 = blockIdx.y * 64, n0 = blockIdx.x * BN;
    const int sr = t >> 2;
    const int sc = (t & 3) * 8;

    const unsigned short* Ag = A + (size_t)(m0 + sr) * K + sc;
    const unsigned short* Wg = W + (size_t)(n0 + sr) * K + sc;

    f32x4 acc[2][NJ];
    #pragma unroll
    for (int i = 0; i < 2; i++)
        #pragma unroll
        for (int j = 0; j < NJ; j++)
            acc[i][j] = (f32x4){0.f, 0.f, 0.f, 0.f};

    const int lm = lane & 15, lk = (lane >> 4) * 8;

    uint4 a0 = *(const uint4*)(Ag);
    uint4 b0 = *(const uint4*)(Wg);
    uint4 b1;
    if constexpr (BN == 128) b1 = *(const uint4*)(Wg + (size_t)64 * K);

    for (int k0 = 0; k0 < K; k0 += 32) {
        __syncthreads();
        *(uint4*)&As[sr * LDP + sc] = a0;
        *(uint4*)&Bs[sr * LDP + sc] = b0;
        if constexpr (BN == 128) *(uint4*)&Bs[(sr + 64) * LDP + sc] = b1;
        __syncthreads();
        if (k0 + 32 < K) {
            a0 = *(const uint4*)(Ag + k0 + 32);
            b0 = *(const uint4*)(Wg + k0 + 32);
            if constexpr (BN == 128)
                b1 = *(const uint4*)(Wg + (size_t)64 * K + k0 + 32);
        }

        short8 af[2], bf[NJ];
        #pragma unroll
        for (int i = 0; i < 2; i++)
            af[i] = *(const short8*)&As[(wr * 32 + i * 16 + lm) * LDP + lk];
        #pragma unroll
        for (int j = 0; j < NJ; j++)
            bf[j] = *(const short8*)&Bs[(wc * (BN / 2) + j * 16 + lm) * LDP + lk];
        #pragma unroll
        for (int i = 0; i < 2; i++)
            #pragma unroll
            for (int j = 0; j < NJ; j++)
                acc[i][j] = __builtin_amdgcn_mfma_f32_16x16x32_bf16(
                    af[i], bf[j], acc[i][j], 0, 0, 0);
    }

    const int lq = lane >> 4;
    #pragma unroll
    for (int j = 0; j < NJ; j++) {
        int col = n0 + wc * (BN / 2) + j * 16 + lm;
        float bv = bias[col];
        #pragma unroll
        for (int i = 0; i < 2; i++) {
            #pragma unroll
            for (int r = 0; r < 4; r++) {
                int row = m0 + wr * 32 + i * 16 + lq * 4 + r;
                float v = acc[i][j][r] + bv;
                if (act) v = 0.5f * v * (1.0f + erff(v * 0.70710678118654752f));
                if (vth && col >= 2 * DD) {
                    vth[vt_index(row, col - 2 * DD)] = f2bfu(v);
                } else {
                    size_t idx = (size_t)row * N + col;
                    if (resid) v += resid[idx];
                    if (outf) outf[idx] = v;
                    if (outb) outb[idx] = f2bfu(v);
                }
            }
        }
    }
}

// ---------------------------------------------------------------------------
// Full-row GEMM (N=256) + residual [+ LayerNorm] fused epilogue.
// Barrier-free K-loop (PROVEN WIN at 1 block/CU: round-2 -11us). A built in
// LDS once; B wave-private panels via depth-4 register ring.
template<bool COMBINE, bool DOLN, int K>
__global__ __launch_bounds__(256) void gemm_ln(
    const unsigned short* __restrict__ A,
    const float* __restrict__ Of, const float2* __restrict__ Ml,
    const unsigned short* __restrict__ W, const float* __restrict__ bias,
    const float* __restrict__ resid,
    const float* __restrict__ g, const float* __restrict__ bt,
    float* __restrict__ outf, unsigned short* __restrict__ outb)
{
    constexpr int LDA = K + 8;       // row stride in shorts (16B-aligned rows)
    constexpr int NS  = K / 32;      // number of 32-wide K steps
    __shared__ __align__(16) unsigned short As[16 * LDA];
    __shared__ float rsum[4][16];
    __shared__ float rsum2[4][16];
    const int t = threadIdx.x;
    const int lane = t & 63, wave = t >> 6;
    const int m0 = blockIdx.x * 16;
    const int lm = lane & 15, quad = lane >> 4;

    // ---- issue first B-ring loads before A-staging so they overlap it
    const unsigned short* Wp = W + (size_t)(wave * 64 + lm) * K + quad * 8;
    short8 bf[4][4];
    #pragma unroll
    for (int s = 0; s < 4; s++)
        #pragma unroll
        for (int j = 0; j < 4; j++)
            bf[s][j] = *(const short8*)(Wp + (size_t)(j * 16) * K + s * 32);

    // ---- Phase 1: build As[16][K] once (all 256 threads participate)
    if (COMBINE) {
        // K == 256 here. thread -> (row, 16-col group); 32 cols per head.
        const int row = t >> 4, cg = t & 15;
        const int token = m0 + row;
        const int h = cg >> 1;
        float2 ml[NSEG];
        float M = -1e30f;
        #pragma unroll
        for (int s = 0; s < NSEG; s++) {
            ml[s] = Ml[((size_t)s * NTOK + token) * HH + h];
            M = fmaxf(M, ml[s].x);
        }
        float wgt[NSEG]; float denom = 0.f;
        #pragma unroll
        for (int s = 0; s < NSEG; s++) {
            wgt[s] = __expf(ml[s].x - M);
            denom += ml[s].y * wgt[s];
        }
        const float inv = 1.0f / denom;
        float a16[16];
        #pragma unroll
        for (int c = 0; c < 16; c++) a16[c] = 0.f;
        #pragma unroll
        for (int s = 0; s < NSEG; s++) {
            const float* p = Of + ((size_t)s * NTOK + token) * DD + cg * 16;
            #pragma unroll
            for (int c4 = 0; c4 < 4; c4++) {
                float4 x = *(const float4*)(p + c4 * 4);
                a16[c4 * 4 + 0] += x.x * wgt[s];
                a16[c4 * 4 + 1] += x.y * wgt[s];
                a16[c4 * 4 + 2] += x.z * wgt[s];
                a16[c4 * 4 + 3] += x.w * wgt[s];
            }
        }
        __align__(16) unsigned short ab[16];
        #pragma unroll
        for (int c = 0; c < 16; c++) ab[c] = f2bfu(a16[c] * inv);
        *(uint4*)&As[row * LDA + cg * 16]     = *(uint4*)&ab[0];
        *(uint4*)&As[row * LDA + cg * 16 + 8] = *(uint4*)&ab[8];
    } else {
        #pragma unroll
        for (int u = t; u < 16 * (K / 8); u += 256) {
            int row = u / (K / 8), cg = u % (K / 8);   // pow2 -> shifts
            *(uint4*)&As[row * LDA + cg * 8] =
                *(const uint4*)(A + (size_t)(m0 + row) * K + cg * 8);
        }
    }
    __syncthreads();

    // ---- Phase 2: barrier-free K loop, depth-4 register ring on B
    f32x4 acc[4];
    #pragma unroll
    for (int j = 0; j < 4; j++) acc[j] = (f32x4){0.f, 0.f, 0.f, 0.f};

    #pragma unroll
    for (int k = 0; k < NS; k++) {
        const int r4 = k & 3;
        short8 af = *(const short8*)&As[lm * LDA + k * 32 + quad * 8];
        #pragma unroll
        for (int j = 0; j < 4; j++)
            acc[j] = __builtin_amdgcn_mfma_f32_16x16x32_bf16(
                af, bf[r4][j], acc[j], 0, 0, 0);
        if (k + 4 < NS) {
            #pragma unroll
            for (int j = 0; j < 4; j++)
                bf[r4][j] = *(const short8*)(Wp + (size_t)(j * 16) * K
                                             + (k + 4) * 32);
        }
    }

    // ---- epilogue: bias + resid [+ per-row LayerNorm].
    // Wave w holds rows (quad*4+r) x cols (64w + 16j + lm).
    #pragma unroll
    for (int j = 0; j < 4; j++) {
        int col = wave * 64 + j * 16 + lm;
        float bv = bias[col];
        #pragma unroll
        for (int r = 0; r < 4; r++) {
            int row = m0 + quad * 4 + r;
            acc[j][r] += bv + resid[(size_t)row * DD + col];
        }
    }
    if (!DOLN) {
        #pragma unroll
        for (int j = 0; j < 4; j++) {
            int col = wave * 64 + j * 16 + lm;
            #pragma unroll
            for (int r = 0; r < 4; r++) {
                int row = m0 + quad * 4 + r;
                size_t idx = (size_t)row * DD + col;
                if (outf) outf[idx] = acc[j][r];
                if (outb) outb[idx] = f2bfu(acc[j][r]);
            }
        }
        return;
    }
    #pragma unroll
    for (int r = 0; r < 4; r++) {
        float s = 0.f;
        #pragma unroll
        for (int j = 0; j < 4; j++) s += acc[j][r];
        s += __shfl_xor(s, 1, 64); s += __shfl_xor(s, 2, 64);
        s += __shfl_xor(s, 4, 64); s += __shfl_xor(s, 8, 64);
        if (lm == 0) rsum[wave][quad * 4 + r] = s;
    }
    __syncthreads();
    float mean_[4];
    #pragma unroll
    for (int r = 0; r < 4; r++) {
        int ri = quad * 4 + r;
        mean_[r] = (rsum[0][ri] + rsum[1][ri] + rsum[2][ri] + rsum[3][ri])
                 * (1.0f / 256.0f);
    }
    #pragma unroll
    for (int r = 0; r < 4; r++) {
        float s2 = 0.f;
        #pragma unroll
        for (int j = 0; j < 4; j++) {
            float d = acc[j][r] - mean_[r];
            s2 += d * d;
        }
        s2 += __shfl_xor(s2, 1, 64); s2 += __shfl_xor(s2, 2, 64);
        s2 += __shfl_xor(s2, 4, 64); s2 += __shfl_xor(s2, 8, 64);
        if (lm == 0) rsum2[wave][quad * 4 + r] = s2;
    }
    __syncthreads();
    float rstd[4];
    #pragma unroll
    for (int r = 0; r < 4; r++) {
        int ri = quad * 4 + r;
        rstd[r] = rsqrtf((rsum2[0][ri] + rsum2[1][ri] + rsum2[2][ri] + rsum2[3][ri])
                         * (1.0f / 256.0f) + 1e-5f);
    }
    #pragma unroll
    for (int j = 0; j < 4; j++) {
        int col = wave * 64 + j * 16 + lm;
        float gv = g[col], bv2 = bt[col];
        #pragma unroll
        for (int r = 0; r < 4; r++) {
            int row = m0 + quad * 4 + r;
            float ov = (acc[j][r] - mean_[r]) * rstd[r] * gv + bv2;
            size_t idx = (size_t)row * DD + col;
            if (outf) outf[idx] = ov;
            if (outb) outb[idx] = f2bfu(ov);
        }
    }
}

// ---------------------------------------------------------------------------
// Split (hi/lo bf16 ~ fp32) MFMA GEMM for the layer-0 QKV projection.
// Q,K -> packed hi/lo; V -> transposed VT (hi only). Register-prefetched.
// 64x64 tile -> 768 blocks = 3/CU even (round-6 win).
__global__ __launch_bounds__(256) void gemm_mfma_split(
    const unsigned short* __restrict__ Ah, const unsigned short* __restrict__ Al,
    const unsigned short* __restrict__ Wh, const unsigned short* __restrict__ Wl,
    const float* __restrict__ bias,
    unsigned short* __restrict__ outh, unsigned short* __restrict__ outl,
    unsigned short* __restrict__ vth,
    int M, int N, int K)
{
    __shared__ __align__(16) unsigned short Ash[64 * LDP];
    __shared__ __align__(16) unsigned short Asl[64 * LDP];
    __shared__ __align__(16) unsigned short Bsh[64 * LDP];
    __shared__ __align__(16) unsigned short Bsl[64 * LDP];
    const int t = threadIdx.x;
    const int lane = t & 63, wave = t >> 6;
    const int wr = wave >> 1, wc = wave & 1;
    const int m0 = blockIdx.y * 64, n0 = blockIdx.x * 64;
    const int sr = t >> 2;
    const int sc = (t & 3) * 8;

    const size_t oA = (size_t)(m0 + sr) * K + sc;
    const size_t oW = (size_t)(n0 + sr) * K + sc;

    f32x4 acc[2][2];
    #pragma unroll
    for (int i = 0; i < 2; i++)
        #pragma unroll
        for (int j = 0; j < 2; j++)
            acc[i][j] = (f32x4){0.f, 0.f, 0.f, 0.f};

    const int lm = lane & 15, lk = (lane >> 4) * 8;

    uint4 ah0 = *(const uint4*)(Ah + oA);
    uint4 al0 = *(const uint4*)(Al + oA);
    uint4 bh0 = *(const uint4*)(Wh + oW);
    uint4 bl0 = *(const uint4*)(Wl + oW);

    for (int k0 = 0; k0 < K; k0 += 32) {
        __syncthreads();
        *(uint4*)&Ash[sr * LDP + sc] = ah0;
        *(uint4*)&Asl[sr * LDP + sc] = al0;
        *(uint4*)&Bsh[sr * LDP + sc] = bh0;
        *(uint4*)&Bsl[sr * LDP + sc] = bl0;
        __syncthreads();
        if (k0 + 32 < K) {
            ah0 = *(const uint4*)(Ah + oA + k0 + 32);
            al0 = *(const uint4*)(Al + oA + k0 + 32);
            bh0 = *(const uint4*)(Wh + oW + k0 + 32);
            bl0 = *(const uint4*)(Wl + oW + k0 + 32);
        }

        short8 afh[2], afl[2], bfh[2], bfl[2];
        #pragma unroll
        for (int i = 0; i < 2; i++) {
            afh[i] = *(const short8*)&Ash[(wr * 32 + i * 16 + lm) * LDP + lk];
            afl[i] = *(const short8*)&Asl[(wr * 32 + i * 16 + lm) * LDP + lk];
        }
        #pragma unroll
        for (int j = 0; j < 2; j++) {
            bfh[j] = *(const short8*)&Bsh[(wc * 32 + j * 16 + lm) * LDP + lk];
            bfl[j] = *(const short8*)&Bsl[(wc * 32 + j * 16 + lm) * LDP + lk];
        }
        #pragma unroll
        for (int i = 0; i < 2; i++)
            #pragma unroll
            for (int j = 0; j < 2; j++) {
                acc[i][j] = __builtin_amdgcn_mfma_f32_16x16x32_bf16(
                    afl[i], bfh[j], acc[i][j], 0, 0, 0);
                acc[i][j] = __builtin_amdgcn_mfma_f32_16x16x32_bf16(
                    afh[i], bfl[j], acc[i][j], 0, 0, 0);
                acc[i][j] = __builtin_amdgcn_mfma_f32_16x16x32_bf16(
                    afh[i], bfh[j], acc[i][j], 0, 0, 0);
            }
    }

    const int lq = lane >> 4;
    #pragma unroll
    for (int j = 0; j < 2; j++) {
        int col = n0 + wc * 32 + j * 16 + lm;
        float bv = bias[col];
        #pragma unroll
        for (int i = 0; i < 2; i++) {
            #pragma unroll
            for (int r = 0; r < 4; r++) {
                int row = m0 + wr * 32 + i * 16 + lq * 4 + r;
                float v = acc[i][j][r] + bv;
                unsigned short h = f2bfu(v);
                if (col >= 2 * DD) {
                    vth[vt_index(row, col - 2 * DD)] = h;
                } else {
                    size_t idx = (size_t)row * N + col;
                    outh[idx] = h;
                    outl[idx] = f2bfu(v - bfu2f(h));
                }
            }
        }
    }
}

// ---------------------------------------------------------------------------
// MFMA flash attention, SPLIT (hi/lo) scores with ONLINE softmax — layer-0
// full attention only. V hi-only. Swapped QK^T (round-5 win). Split-K NSEG=4
// (2048 blocks, 5-6 resident/CU — round-7: TLP load-bearing).
// Round 10: s_setprio(1) around MFMA clusters (T5) — co-resident blocks sit
// at different k-tile phases, so the hint lets MFMA-issuing waves win
// arbitration over staging waves (m191 attn regime, +4-7%).
__global__ __launch_bounds__(256) void attn_split(
    const unsigned short* __restrict__ qkvh,
    const unsigned short* __restrict__ qkvl,
    const unsigned short* __restrict__ vth,
    float* __restrict__ Of, float2* __restrict__ Ml)
{
    __shared__ __align__(16) unsigned short Ks [64 * 40];
    __shared__ __align__(16) unsigned short Vt [32 * 72];
    __shared__ __align__(16) unsigned short Ps [64 * 72];
    __shared__ __align__(16) unsigned short Ksl[64 * 40];

    const int t = threadIdx.x;
    const int wave = t >> 6, lane = t & 63;
    const int lm = lane & 15, quad = lane >> 4;
    const int i0 = blockIdx.x * 64, h = blockIdx.y;
    const int z = blockIdx.z;
    const int b = z >> 2, seg = z & (NSEG - 1);
    const int sr = t >> 2, sc8 = (t & 3) * 8;
    const int vd = t >> 3, vs8 = (t & 7) * 8;

    const size_t qoff = ((size_t)(b * SS) + i0 + 16 * wave + lm) * D3 + h * HD + quad * 8;
    short8 qh = *(const short8*)(qkvh + qoff);
    short8 ql = *(const short8*)(qkvl + qoff);

    const unsigned short* Kg  = qkvh + (size_t)(b * SS) * D3 + DD + h * HD;
    const unsigned short* Klg = qkvl + (size_t)(b * SS) * D3 + DD + h * HD;
    const unsigned short* Vg  = vth + ((size_t)b * HH + h) * HD * SS;

    float m = -1e30f, l = 0.f;
    f32x4 o[2];
    o[0] = (f32x4){0.f, 0.f, 0.f, 0.f};
    o[1] = (f32x4){0.f, 0.f, 0.f, 0.f};

    const int per = (SS / 64) / NSEG;
    const int s0 = seg * per, s1 = s0 + per - 1;
    const float scl = 0.17677669529663688f;  // 1/sqrt(32)

    short8 kreg  = *(const short8*)(Kg  + (size_t)(s0 * 64 + sr) * D3 + sc8);
    short8 kregl = *(const short8*)(Klg + (size_t)(s0 * 64 + sr) * D3 + sc8);
    short8 vreg  = *(const short8*)(Vg  + (size_t)vd * SS + s0 * 64 + vs8);

    for (int kt = s0; kt <= s1; kt++) {
        const int k0 = kt * 64;
        __syncthreads();
        *(short8*)&Ks [sr * 40 + sc8] = kreg;
        *(short8*)&Ksl[sr * 40 + sc8] = kregl;
        *(short8*)&Vt [vd * 72 + vs8] = vreg;
        __syncthreads();
        if (kt < s1) {
            kreg  = *(const short8*)(Kg  + (size_t)(k0 + 64 + sr) * D3 + sc8);
            kregl = *(const short8*)(Klg + (size_t)(k0 + 64 + sr) * D3 + sc8);
            vreg  = *(const short8*)(Vg  + (size_t)vd * SS + k0 + 64 + vs8);
        }

        // scores: vs[cb][r] = S[k = 16cb + quad*4 + r][q = lm] * scl
        float vs[4][4];
        __builtin_amdgcn_s_setprio(1);
        #pragma unroll
        for (int cb = 0; cb < 4; cb++) {
            short8 kf  = *(const short8*)&Ks [(16 * cb + lm) * 40 + quad * 8];
            short8 kfl = *(const short8*)&Ksl[(16 * cb + lm) * 40 + quad * 8];
            f32x4 a = (f32x4){0.f, 0.f, 0.f, 0.f};
            a = __builtin_amdgcn_mfma_f32_16x16x32_bf16(kf,  ql, a, 0, 0, 0);
            a = __builtin_amdgcn_mfma_f32_16x16x32_bf16(kfl, qh, a, 0, 0, 0);
            a = __builtin_amdgcn_mfma_f32_16x16x32_bf16(kf,  qh, a, 0, 0, 0);
            #pragma unroll
            for (int r = 0; r < 4; r++) vs[cb][r] = a[r] * scl;
        }
        __builtin_amdgcn_s_setprio(0);

        // row max: in-lane tree over 16 + cross-quad combine
        float tm = fmaxf(fmaxf(vs[0][0], vs[0][1]), fmaxf(vs[0][2], vs[0][3]));
        #pragma unroll
        for (int cb = 1; cb < 4; cb++)
            tm = fmaxf(tm, fmaxf(fmaxf(vs[cb][0], vs[cb][1]),
                                 fmaxf(vs[cb][2], vs[cb][3])));
        tm = fmaxf(tm, __shfl_xor(tm, 16, 64));
        tm = fmaxf(tm, __shfl_xor(tm, 32, 64));
        float mn = fmaxf(m, tm);
        float alpha = __expf(m - mn);
        m = mn;

        // p = exp(s - mn), in-lane partial sum, packed b64 store of P^T
        float ps = 0.f;
        #pragma unroll
        for (int cb = 0; cb < 4; cb++) {
            float p0 = __expf(vs[cb][0] - mn), p1 = __expf(vs[cb][1] - mn);
            float p2 = __expf(vs[cb][2] - mn), p3 = __expf(vs[cb][3] - mn);
            ps += (p0 + p1) + (p2 + p3);
            uint2 pk;
            pk.x = (unsigned)f2bfu(p0) | ((unsigned)f2bfu(p1) << 16);
            pk.y = (unsigned)f2bfu(p2) | ((unsigned)f2bfu(p3) << 16);
            *(uint2*)&Ps[(16 * wave + lm) * 72 + 16 * cb + quad * 4] = pk;
        }
        ps += __shfl_xor(ps, 16, 64);
        ps += __shfl_xor(ps, 32, 64);
        l = l * alpha + ps;

        // redistribute alpha from q=lm layout to o row-layout (q=quad*4+r)
        float ar[4];
        #pragma unroll
        for (int r = 0; r < 4; r++) ar[r] = __shfl(alpha, quad * 4 + r, 64);
        #pragma unroll
        for (int r = 0; r < 4; r++) { o[0][r] *= ar[r]; o[1][r] *= ar[r]; }

        __builtin_amdgcn_s_setprio(1);
        #pragma unroll
        for (int kc = 0; kc < 2; kc++) {
            short8 pf = *(const short8*)&Ps[(16 * wave + lm) * 72 + 32 * kc + quad * 8];
            #pragma unroll
            for (int nh = 0; nh < 2; nh++) {
                short8 vf = *(const short8*)&Vt[(16 * nh + lm) * 72 + 32 * kc + quad * 8];
                o[nh] = __builtin_amdgcn_mfma_f32_16x16x32_bf16(pf, vf, o[nh], 0, 0, 0);
            }
        }
        __builtin_amdgcn_s_setprio(0);
    }

    #pragma unroll
    for (int r = 0; r < 4; r++) {
        int row = i0 + 16 * wave + quad * 4 + r;
        size_t base = ((size_t)seg * NTOK + b * SS + row) * DD + h * HD + lm;
        Of[base]      = o[0][r];
        Of[base + 16] = o[1][r];
    }
    if (quad == 0)
        Ml[((size_t)seg * NTOK + b * SS + i0 + 16 * wave + lm) * HH + h] =
            make_float2(m, l);
}

// ---------------------------------------------------------------------------
// MFMA flash attention, FIXED-MAX softmax (post-LN inputs: scores O(1)).
// nseg==1: normalized bf16 out. nseg>1: f32 unnormalized partials + (32,l).
// Swapped QK^T (round-5) — zero in-loop shfl; l reduced once at the end.
// Round 10: s_setprio(1) around the PV MFMA cluster (T5).
__global__ __launch_bounds__(256) void attn_fixed(
    const unsigned short* __restrict__ qkvh,
    const unsigned short* __restrict__ vth,
    unsigned short* __restrict__ outb,
    float* __restrict__ Of, float2* __restrict__ Ml,
    int win, int nseg)
{
    __shared__ __align__(16) unsigned short Ks[64 * 40];
    __shared__ __align__(16) unsigned short Vt[32 * 72];
    __shared__ __align__(16) unsigned short Ps[64 * 72];

    const int t = threadIdx.x;
    const int wave = t >> 6, lane = t & 63;
    const int lm = lane & 15, quad = lane >> 4;
    const int i0 = blockIdx.x * 64, h = blockIdx.y;
    const int z = blockIdx.z;
    const int b = z / nseg, seg = z - b * nseg;
    const int sr = t >> 2, sc8 = (t & 3) * 8;
    const int vd = t >> 3, vs8 = (t & 7) * 8;

    const size_t qoff = ((size_t)(b * SS) + i0 + 16 * wave + lm) * D3 + h * HD + quad * 8;
    short8 qh = *(const short8*)(qkvh + qoff);

    const unsigned short* Kg = qkvh + (size_t)(b * SS) * D3 + DD + h * HD;
    const unsigned short* Vg = vth + ((size_t)b * HH + h) * HD * SS;

    float l = 0.f;               // per-lane partial sum for q = lm
    f32x4 o[2];
    o[0] = (f32x4){0.f, 0.f, 0.f, 0.f};
    o[1] = (f32x4){0.f, 0.f, 0.f, 0.f};

    int t0 = 0, t1 = SS / 64 - 1;
    const bool masked = (win < SS);
    if (masked) {
        t0 = (i0 - win) >> 6;        if (t0 < 0) t0 = 0;
        t1 = (i0 + 63 + win) >> 6;   if (t1 > SS / 64 - 1) t1 = SS / 64 - 1;
    }
    const int per = (t1 - t0 + nseg) / nseg;
    const int s0 = t0 + seg * per;
    const int s1 = (s0 + per - 1 < t1) ? (s0 + per - 1) : t1;
    const float scl = 0.17677669529663688f;  // 1/sqrt(32)
    const float M0 = 32.0f;                   // fixed softmax shift

    const int qrow = i0 + 16 * wave + lm;     // this lane's q (swapped layout)

    short8 kreg = *(const short8*)(Kg + (size_t)(s0 * 64 + sr) * D3 + sc8);
    short8 vreg = *(const short8*)(Vg + (size_t)vd * SS + s0 * 64 + vs8);

    for (int kt = s0; kt <= s1; kt++) {
        const int k0 = kt * 64;
        __syncthreads();
        *(short8*)&Ks[sr * 40 + sc8] = kreg;
        *(short8*)&Vt[vd * 72 + vs8] = vreg;
        __syncthreads();
        if (kt < s1) {
            kreg = *(const short8*)(Kg + (size_t)(k0 + 64 + sr) * D3 + sc8);
            vreg = *(const short8*)(Vg + (size_t)vd * SS + k0 + 64 + vs8);
        }

        #pragma unroll
        for (int cb = 0; cb < 4; cb++) {
            short8 kf = *(const short8*)&Ks[(16 * cb + lm) * 40 + quad * 8];
            f32x4 a = (f32x4){0.f, 0.f, 0.f, 0.f};
            __builtin_amdgcn_s_setprio(1);
            a = __builtin_amdgcn_mfma_f32_16x16x32_bf16(kf, qh, a, 0, 0, 0);
            __builtin_amdgcn_s_setprio(0);
            // a[r] = S[k = k0 + 16cb + quad*4 + r][q = qrow]
            float p[4];
            #pragma unroll
            for (int r = 0; r < 4; r++) {
                float v = a[r] * scl;
                if (masked) {
                    int di = qrow - (k0 + 16 * cb + quad * 4 + r);
                    if (di > win || di < -win) v = -1e30f;
                }
                p[r] = __expf(v - M0);
            }
            l += (p[0] + p[1]) + (p[2] + p[3]);
            uint2 pk;
            pk.x = (unsigned)f2bfu(p[0]) | ((unsigned)f2bfu(p[1]) << 16);
            pk.y = (unsigned)f2bfu(p[2]) | ((unsigned)f2bfu(p[3]) << 16);
            *(uint2*)&Ps[(16 * wave + lm) * 72 + 16 * cb + quad * 4] = pk;
        }
        // Ps region is wave-private — no barrier needed

        __builtin_amdgcn_s_setprio(1);
        #pragma unroll
        for (int kc = 0; kc < 2; kc++) {
            short8 pf = *(const short8*)&Ps[(16 * wave + lm) * 72 + 32 * kc + quad * 8];
            #pragma unroll
            for (int nh = 0; nh < 2; nh++) {
                short8 vf = *(const short8*)&Vt[(16 * nh + lm) * 72 + 32 * kc + quad * 8];
                o[nh] = __builtin_amdgcn_mfma_f32_16x16x32_bf16(pf, vf, o[nh], 0, 0, 0);
            }
        }
        __builtin_amdgcn_s_setprio(0);
    }

    // full row sum for q = lm: combine the 4 quad partials
    l += __shfl_xor(l, 16, 64);
    l += __shfl_xor(l, 32, 64);

    if (nseg == 1) {
        // redistribute l from q=lm layout to o row-layout (q = quad*4+r)
        #pragma unroll
        for (int r = 0; r < 4; r++) {
            float lr = __shfl(l, quad * 4 + r, 64);
            float invl = 1.0f / lr;
            size_t base = ((size_t)(b * SS) + i0 + 16 * wave + quad * 4 + r) * DD + h * HD + lm;
            outb[base]      = f2bfu(o[0][r] * invl);
            outb[base + 16] = f2bfu(o[1][r] * invl);
        }
    } else {
        #pragma unroll
        for (int r = 0; r < 4; r++) {
            int row = i0 + 16 * wave + quad * 4 + r;
            size_t base = ((size_t)seg * NTOK + b * SS + row) * DD + h * HD + lm;
            Of[base]      = o[0][r];
            Of[base + 16] = o[1][r];
        }
        if (quad == 0)
            Ml[((size_t)seg * NTOK + b * SS + i0 + 16 * wave + lm) * HH + h] =
                make_float2(M0, l);
    }
}

// ---------------------------------------------------------------------------
extern "C" void kernel_launch(void* const* d_in, const int* in_sizes, int n_in,
                              void* d_out, int out_size, void* d_ws, size_t ws_size,
                              hipStream_t stream)
{
    const float* xin   = (const float*)d_in[0];
    const float* scale = (const float*)d_in[1];
    const float* Win_a = (const float*)d_in[2];
    const float* bin_a = (const float*)d_in[3];
    const float* Wout_a= (const float*)d_in[4];
    const float* bout_a= (const float*)d_in[5];
    const float* Win_e = (const float*)d_in[6];
    const float* bin_e = (const float*)d_in[7];
    const float* Wout_e= (const float*)d_in[8];
    const float* bout_e= (const float*)d_in[9];
    const float* ln1_g = (const float*)d_in[10];
    const float* ln1_b = (const float*)d_in[11];
    const float* ln2_g = (const float*)d_in[12];
    const float* ln2_b = (const float*)d_in[13];
    const float* W1    = (const float*)d_in[14];
    const float* b1    = (const float*)d_in[15];
    const float* W2    = (const float*)d_in[16];
    const float* b2    = (const float*)d_in[17];
    const float* lnf_g = (const float*)d_in[18];
    const float* lnf_b = (const float*)d_in[19];

    char* ws = (char*)d_ws;
    float* X    = (float*)ws;                     ws += (size_t)NTOK * DD * 4;
    float* X2   = (float*)ws;                     ws += (size_t)NTOK * DD * 4;
    unsigned short* Xb   = (unsigned short*)ws;   ws += (size_t)NTOK * DD * 2;
    unsigned short* Xlb  = (unsigned short*)ws;   ws += (size_t)NTOK * DD * 2;
    unsigned short* X2b  = (unsigned short*)ws;   ws += (size_t)NTOK * DD * 2;
    unsigned short* ATb  = (unsigned short*)ws;   ws += (size_t)NTOK * DD * 2;
    unsigned short* QKVb = (unsigned short*)ws;   ws += (size_t)NTOK * D3 * 2;
    unsigned short* QKVl = (unsigned short*)ws;   ws += (size_t)NTOK * D3 * 2;
    unsigned short* VTh  = (unsigned short*)ws;   ws += (size_t)NTOK * DD * 2;
    unsigned short* HMLb = (unsigned short*)ws;   ws += (size_t)NTOK * MLP * 2;
    unsigned short* Wb   = (unsigned short*)ws;   ws += (size_t)W_TOT * 2;
    unsigned short* Wl0  = (unsigned short*)ws;   ws += (size_t)WL0 * 2;
    float2* Ml           = (float2*)ws;           ws += (size_t)NSEG * NTOK * HH * 8;
    float* Of            = (float*)ws;            ws += (size_t)NSEG * NTOK * DD * 4;

    unsigned short* WinA_b  = Wb + 0;
    unsigned short* WoutA_b = Wb + 393216;
    unsigned short* WinE_b  = Wb + 524288;
    unsigned short* WoutE_b = Wb + 917504;
    unsigned short* W1_b    = Wb + 1048576;
    unsigned short* W2_b    = Wb + 1572864;

    prep_kernel<<<WBLK4 + PBLK4, 256, 0, stream>>>(
        Win_a, Wout_a, Win_e, Wout_e, W1, W2, Wb, Wl0,
        xin, scale, X, Xb, Xlb);

    float* cur = X;            float* oth = X2;
    unsigned short* curb = Xb; unsigned short* othb = X2b;

    for (int l = 0; l < 2; l++) {
        // --- full self-attention (split-K NSEG, combine+LN fused into Wout)
        if (l == 0) {
            gemm_mfma_split<<<dim3(D3 / 64, NTOK / 64), 256, 0, stream>>>(
                Xb, Xlb, WinA_b, Wl0, bin_a, QKVb, QKVl, VTh, NTOK, D3, DD);
            attn_split<<<dim3(SS / 64, HH, BB * NSEG), 256, 0, stream>>>(
                QKVb, QKVl, VTh, Of, Ml);
        } else {
            gemm_mfma<64><<<dim3(D3 / 64, NTOK / 64), 256, 0, stream>>>(
                curb, WinA_b + (size_t)l * D3 * DD, bin_a + (size_t)l * D3,
                nullptr, nullptr, QKVb, VTh, NTOK, D3, DD, 0);
            attn_fixed<<<dim3(SS / 64, HH, BB * NSEG), 256, 0, stream>>>(
                QKVb, VTh, nullptr, Of, Ml, 1 << 28, NSEG);
        }
        gemm_ln<true, true, DD><<<NTOK / 16, 256, 0, stream>>>(
            nullptr, Of, Ml, WoutA_b + (size_t)l * DD * DD,
            bout_a + (size_t)l * DD, cur,
            ln1_g + l * DD, ln1_b + l * DD, oth, othb);

        // --- banded self-attention (|i-j| <= 64), LN fused into Wout
        gemm_mfma<64><<<dim3(D3 / 64, NTOK / 64), 256, 0, stream>>>(
            othb, WinE_b + (size_t)l * D3 * DD, bin_e + (size_t)l * D3,
            nullptr, nullptr, QKVb, VTh, NTOK, D3, DD, 0);
        attn_fixed<<<dim3(SS / 64, HH, BB), 256, 0, stream>>>(
            QKVb, VTh, ATb, nullptr, nullptr, 64, 1);
        gemm_ln<false, true, DD><<<NTOK / 16, 256, 0, stream>>>(
            ATb, nullptr, nullptr, WoutE_b + (size_t)l * DD * DD,
            bout_e + (size_t)l * DD, oth,
            ln2_g + l * DD, ln2_b + l * DD, cur, curb);
        // attended now in cur/curb

        // --- MLP with exact gelu; layer-1's W2 fuses the final LayerNorm
        gemm_mfma<64><<<dim3(MLP / 64, NTOK / 64), 256, 0, stream>>>(
            curb, W1_b + (size_t)l * MLP * DD, b1 + (size_t)l * MLP,
            nullptr, nullptr, HMLb, nullptr, NTOK, MLP, DD, 1);
        if (l == 0) {
            // full-row no-LN GEMM: grid 256 (full machine)
            gemm_ln<false, false, MLP><<<NTOK / 16, 256, 0, stream>>>(
                HMLb, nullptr, nullptr, W2_b + (size_t)l * DD * MLP,
                b2 + (size_t)l * DD, cur,
                nullptr, nullptr, oth, othb);
            float* tf = cur; cur = oth; oth = tf;
            unsigned short* tb = curb; curb = othb; othb = tb;
        } else {
            gemm_ln<false, true, MLP><<<NTOK / 16, 256, 0, stream>>>(
                HMLb, nullptr, nullptr, W2_b + (size_t)l * DD * MLP,
                b2 + (size_t)l * DD, cur,
                lnf_g, lnf_b, (float*)d_out, nullptr);
        }
    }
}